// Round 7
// baseline (175.488 us; speedup 1.0000x reference)
//
#include <hip/hip_runtime.h>
#include <hip/hip_bf16.h>
#include <stdint.h>

#define NBATCH 4
#define NV 2048
#define NC 8192
#define DD 64

typedef __attribute__((ext_vector_type(8))) short s16x8;
typedef __attribute__((ext_vector_type(4))) float fx4;
typedef __attribute__((ext_vector_type(8))) unsigned short u16x8;
typedef __attribute__((ext_vector_type(4))) int i32x4;
typedef __attribute__((ext_vector_type(2))) unsigned int u32x2;

static __device__ __forceinline__ unsigned short bf16_rne(float x) {
    union { float f; unsigned int u; } v; v.f = x;
    unsigned int u = v.u;
    u += 0x7FFFu + ((u >> 16) & 1u);
    return (unsigned short)(u >> 16);
}
static __device__ __forceinline__ float bf16_f32(unsigned short h) {
    union { unsigned int u; float f; } v; v.u = ((unsigned int)h) << 16;
    return v.f;
}
static __device__ __forceinline__ void gload_lds16(const void* g, void* l) {
    __builtin_amdgcn_global_load_lds(
        (const __attribute__((address_space(1))) unsigned int*)g,
        (__attribute__((address_space(3))) unsigned int*)l, 16, 0, 0);
}

// ---------------------------------------------------------------------------
// K0: s=(pos+neg)/2, d=(pos-neg)/2 of variables @ c_block[pn]^T, quantized to
// int16 (scale 2^12), split hi/lo i8, stored in i8 MFMA B-frag layout:
// chunk kc (64 vars): 4096 B slice at (b*32+kc)*4096; within: dout*64+lg*16+half*8
// ---------------------------------------------------------------------------
__global__ __launch_bounds__(256) void k_prep_pv(
    const float* __restrict__ vars, const float* __restrict__ cblk,
    char* __restrict__ qsh, char* __restrict__ qsl,
    char* __restrict__ qdh, char* __restrict__ qdl)
{
    __shared__ float sv[32][64];
    __shared__ float scb[2][64][65];
    int blk = blockIdx.x;
    int b = blk >> 6, ch = blk & 63;
    int t = threadIdx.x;
    const float* vsrc = vars + ((size_t)b * NV + (size_t)ch * 32) * DD;
    for (int i = t; i < 32 * 64; i += 256) sv[i >> 6][i & 63] = vsrc[i];
    for (int i = t; i < 2 * 64 * 64; i += 256) {
        int pn = i >> 12, dout = (i >> 6) & 63, k = i & 63;
        scb[pn][k][dout] = cblk[i];
    }
    __syncthreads();
    int ks = t >> 6, dout = t & 63;
    unsigned int wsh[2] = {0, 0}, wsl[2] = {0, 0}, wdh[2] = {0, 0}, wdl[2] = {0, 0};
    #pragma unroll
    for (int c8 = 0; c8 < 8; ++c8) {
        int vloc = ks * 8 + c8;
        float ap = 0.f, an = 0.f;
        for (int k = 0; k < 64; ++k) {
            float vv = sv[vloc][k];
            ap += vv * scb[0][k][dout];
            an += vv * scb[1][k][dout];
        }
        float s = (ap + an) * 0.5f, dv = (ap - an) * 0.5f;
        int qs_ = (int)rintf(s * 4096.f);
        int qd_ = (int)rintf(dv * 4096.f);
        qs_ = min(max(qs_, -32511), 32511);
        qd_ = min(max(qd_, -32511), 32511);
        int sh = (qs_ + 128) >> 8, sl = qs_ - (sh << 8);
        int dh = (qd_ + 128) >> 8, dl = qd_ - (dh << 8);
        int w = c8 >> 2, sft = (c8 & 3) * 8;
        wsh[w] |= (unsigned int)(sh & 0xFF) << sft;
        wsl[w] |= (unsigned int)(sl & 0xFF) << sft;
        wdh[w] |= (unsigned int)(dh & 0xFF) << sft;
        wdl[w] |= (unsigned int)(dl & 0xFF) << sft;
    }
    int kc = ch >> 1;
    int lg = ((ch & 1) << 1) | (ks >> 1);
    size_t off = (((size_t)(b * 32 + kc) * 64 + dout) * 4 + lg) * 16 + (ks & 1) * 8;
    *(u32x2*)(qsh + off) = (u32x2){wsh[0], wsh[1]};
    *(u32x2*)(qsl + off) = (u32x2){wsl[0], wsl[1]};
    *(u32x2*)(qdh + off) = (u32x2){wdh[0], wdh[1]};
    *(u32x2*)(qdl + off) = (u32x2){wdl[0], wdl[1]};
}

// ---------------------------------------------------------------------------
// K1: FULL-K i8 phase A: c[b][crow][d] = relu((|A|@s + A@d)/4096 + cb) final.
// 256 blocks x 512 thr: 8 waves, 16-row strip each (128 rows/block), K=2048
// in 32 K64-chunks, i8 planes gload_lds double-buffered (waves 0-3 stage).
// Emits comp 2-bit codes. blk: b = blk&3, rg = blk>>2.
// ---------------------------------------------------------------------------
__global__ __launch_bounds__(512, 4) void k_phaseA(
    const float* __restrict__ cmat,
    const char* __restrict__ qsh, const char* __restrict__ qsl,
    const char* __restrict__ qdh, const char* __restrict__ qdl,
    const float* __restrict__ cb,
    float* __restrict__ cfull, unsigned short* __restrict__ comp)
{
    __shared__ char lds[2][16384];
    int blk = blockIdx.x;
    int b = blk & 3;
    int rg = blk >> 2;
    int t = threadIdx.x;
    int wv = t >> 6, l = t & 63, lr = l & 15, lg = l >> 4;
    int row0 = rg * 128 + wv * 16;
    const float* A0 = cmat + (size_t)b * NC * NV + (size_t)(row0 + lr) * NV + lg * 16;
    unsigned short* compb = comp + (size_t)b * 256 * NC;

    i32x4 ahi[4], alo[4];
    #pragma unroll
    for (int n = 0; n < 4; ++n) { ahi[n] = (i32x4){0,0,0,0}; alo[n] = (i32x4){0,0,0,0}; }

    // prologue: stage chunk 0 + A regs chunk 0
    if (t < 256) {
        size_t gb = ((size_t)(b * 32)) * 4096 + (size_t)t * 16;
        char* lp = &lds[0][t * 16];
        gload_lds16(qsh + gb, lp);
        gload_lds16(qsl + gb, lp + 4096);
        gload_lds16(qdh + gb, lp + 8192);
        gload_lds16(qdl + gb, lp + 12288);
    }
    fx4 xc[4], xn[4];
    #pragma unroll
    for (int j4 = 0; j4 < 4; ++j4) xc[j4] = *(const fx4*)(A0 + j4 * 4);
    __syncthreads();

    int cur = 0;
    #pragma unroll 1
    for (int kc = 0; kc < 32; ++kc) {
        if (kc < 31) {
            if (t < 256) {
                size_t gb = ((size_t)(b * 32 + kc + 1)) * 4096 + (size_t)t * 16;
                char* lp = &lds[cur ^ 1][t * 16];
                gload_lds16(qsh + gb, lp);
                gload_lds16(qsl + gb, lp + 4096);
                gload_lds16(qdh + gb, lp + 8192);
                gload_lds16(qdl + gb, lp + 12288);
            }
            #pragma unroll
            for (int j4 = 0; j4 < 4; ++j4)
                xn[j4] = *(const fx4*)(A0 + (kc + 1) * 64 + j4 * 4);
        }
        // decode A: sgn bytes {0,1,0xFF}, abs bytes {0,1}; comp 2-bit codes
        int tt[16];
        #pragma unroll
        for (int j = 0; j < 16; ++j) tt[j] = (int)xc[j >> 2][j & 3];
        i32x4 Asgn, Aabs;
        #pragma unroll
        for (int w = 0; w < 4; ++w)
            Asgn[w] = (unsigned int)(tt[4*w] & 0xFF) | ((unsigned int)(tt[4*w+1] & 0xFF) << 8)
                    | ((unsigned int)(tt[4*w+2] & 0xFF) << 16) | ((unsigned int)(tt[4*w+3] & 0xFF) << 24);
        #pragma unroll
        for (int w = 0; w < 4; ++w) Aabs[w] = Asgn[w] & 0x01010101;
        {
            unsigned int b0 = 0, b1 = 0;
            #pragma unroll
            for (int j = 0; j < 8; ++j) b0 |= ((unsigned int)tt[j] & 3u) << (2 * j);
            #pragma unroll
            for (int j = 0; j < 8; ++j) b1 |= ((unsigned int)tt[8 + j] & 3u) << (2 * j);
            int v8 = kc * 8 + lg * 2;
            int crow = row0 + lr;
            compb[(size_t)v8 * NC + crow] = (unsigned short)b0;
            compb[(size_t)(v8 + 1) * NC + crow] = (unsigned short)b1;
        }
        // MFMA from LDS
        const char* bufp = lds[cur];
        #pragma unroll
        for (int n = 0; n < 4; ++n) {
            int boff = ((n * 16 + lr) * 4 + lg) * 16;
            i32x4 Bsh = *(const i32x4*)(bufp + boff);
            i32x4 Bsl = *(const i32x4*)(bufp + 4096 + boff);
            i32x4 Bdh = *(const i32x4*)(bufp + 8192 + boff);
            i32x4 Bdl = *(const i32x4*)(bufp + 12288 + boff);
            ahi[n] = __builtin_amdgcn_mfma_i32_16x16x64_i8(Aabs, Bsh, ahi[n], 0, 0, 0);
            ahi[n] = __builtin_amdgcn_mfma_i32_16x16x64_i8(Asgn, Bdh, ahi[n], 0, 0, 0);
            alo[n] = __builtin_amdgcn_mfma_i32_16x16x64_i8(Aabs, Bsl, alo[n], 0, 0, 0);
            alo[n] = __builtin_amdgcn_mfma_i32_16x16x64_i8(Asgn, Bdl, alo[n], 0, 0, 0);
        }
        if (kc < 31) {
            #pragma unroll
            for (int j4 = 0; j4 < 4; ++j4) xc[j4] = xn[j4];
        }
        __syncthreads();
        cur ^= 1;
    }
    // epilogue: c = relu(val/4096 + cb), final write (8 MB, L3-resident)
    float* dst = cfull + ((size_t)b * NC + row0) * DD;
    #pragma unroll
    for (int n = 0; n < 4; ++n) {
        int col = n * 16 + lr;
        float cbv = cb[col];
        #pragma unroll
        for (int r = 0; r < 4; ++r) {
            float v = (float)(ahi[n][r] * 256 + alo[n][r]) * (1.0f / 4096.0f) + cbv;
            dst[(size_t)(lg * 4 + r) * DD + col] = fmaxf(v, 0.f);
        }
    }
}

// ---------------------------------------------------------------------------
// K2: reads final c (relu'd); emit (c@v0^T +/- c@v1^T)/2 hi/lo bf16, tiled
// ---------------------------------------------------------------------------
__global__ __launch_bounds__(256) void k_projC(
    const float* __restrict__ cfull,
    const float* __restrict__ vblk,
    unsigned short* __restrict__ csh, unsigned short* __restrict__ csl,
    unsigned short* __restrict__ cdh, unsigned short* __restrict__ cdl)
{
    __shared__ float src[32][64];
    __shared__ float svb[2][64][65];
    int blk = blockIdx.x;
    int b = blk >> 8, kc = blk & 255;
    int t = threadIdx.x;
    const float* cs = cfull + ((size_t)b * NC + (size_t)kc * 32) * DD;
    for (int i = t; i < 2048; i += 256) src[i >> 6][i & 63] = cs[i];
    for (int i = t; i < 8192; i += 256) {
        int pn = i >> 12, dout = (i >> 6) & 63, k = i & 63;
        svb[pn][k][dout] = vblk[i];
    }
    __syncthreads();
    int ks = t >> 6, dout = t & 63;
    float ap[8] = {0.f, 0.f, 0.f, 0.f, 0.f, 0.f, 0.f, 0.f};
    float an[8] = {0.f, 0.f, 0.f, 0.f, 0.f, 0.f, 0.f, 0.f};
    for (int k = 0; k < 64; ++k) {
        float w0 = svb[0][k][dout], w1 = svb[1][k][dout];
        #pragma unroll
        for (int c8 = 0; c8 < 8; ++c8) {
            float rc = src[ks * 8 + c8][k];
            ap[c8] += rc * w0;
            an[c8] += rc * w1;
        }
    }
    u16x8 vsh, vsl, vdh, vdl;
    #pragma unroll
    for (int c8 = 0; c8 < 8; ++c8) {
        float s = (ap[c8] + an[c8]) * 0.5f, dv = (ap[c8] - an[c8]) * 0.5f;
        unsigned short h = bf16_rne(s);
        vsh[c8] = h; vsl[c8] = bf16_rne(s - bf16_f32(h));
        h = bf16_rne(dv);
        vdh[c8] = h; vdl[c8] = bf16_rne(dv - bf16_f32(h));
    }
    size_t obase = (size_t)b * NC * DD + (((size_t)kc * 4 + ks) * 64 + dout) * 8;
    *(u16x8*)(csh + obase) = vsh;
    *(u16x8*)(csl + obase) = vsl;
    *(u16x8*)(cdh + obase) = vdh;
    *(u16x8*)(cdl + obase) = vdl;
}

// ---------------------------------------------------------------------------
// K3: npart[q][b][v][d] = |A|@(csh+csl) + A@(cdh+cdl) bf16, A from comp codes.
// 256-row 4-wave blocks, K64 chunks, global_load_lds double-buffer.
// grid 512 x 256. blk = rg*64 + (b*16+q)  (same-(b,q) -> same XCD).
// ---------------------------------------------------------------------------
__global__ __launch_bounds__(256, 2) void k_phaseB(
    const unsigned short* __restrict__ comp,
    const unsigned short* __restrict__ csh, const unsigned short* __restrict__ csl,
    const unsigned short* __restrict__ cdh, const unsigned short* __restrict__ cdl,
    float* __restrict__ npart)
{
    __shared__ short lds[2][16384];
    int blk = blockIdx.x;
    int combo = blk & 63;
    int rg = blk >> 6;
    int b = combo >> 4;
    int q = combo & 15;
    int t = threadIdx.x;
    int wv = t >> 6, l = t & 63, lr = l & 15, lg = l >> 4;
    int v0 = rg * 256 + wv * 64;
    const unsigned short* compb = comp + (size_t)b * 256 * NC;
    const size_t cvb = (size_t)b * NC * DD;
    int sh_ = 2 * (lr & 7);
    const unsigned short* cp[4];
    #pragma unroll
    for (int rt = 0; rt < 4; ++rt)
        cp[rt] = compb + (size_t)((v0 + rt * 16 + lr) >> 3) * NC + q * 512 + lg * 8;

    fx4 acc[4][4];
    #pragma unroll
    for (int i = 0; i < 4; ++i)
        #pragma unroll
        for (int j = 0; j < 4; ++j) acc[i][j] = (fx4){0.f, 0.f, 0.f, 0.f};

    // prologue: stage chunk 0 + comp chunk 0
    {
        size_t gb = cvb + (size_t)(q * 8) * 4096 + (size_t)t * 8;   // shorts
        short* lp = &lds[0][t * 8];
        gload_lds16(csh + gb, lp);           gload_lds16(csh + gb + 2048, lp + 2048);
        gload_lds16(csl + gb, lp + 4096);    gload_lds16(csl + gb + 2048, lp + 6144);
        gload_lds16(cdh + gb, lp + 8192);    gload_lds16(cdh + gb + 2048, lp + 10240);
        gload_lds16(cdl + gb, lp + 12288);   gload_lds16(cdl + gb + 2048, lp + 14336);
    }
    u16x8 uc[4][2], un[4][2];
    #pragma unroll
    for (int rt = 0; rt < 4; ++rt) {
        uc[rt][0] = *(const u16x8*)(cp[rt]);
        uc[rt][1] = *(const u16x8*)(cp[rt] + 32);
    }
    __syncthreads();

    int cur = 0;
    #pragma unroll 1
    for (int cc = 0; cc < 8; ++cc) {
        if (cc < 7) {
            size_t gb = cvb + (size_t)(q * 8 + cc + 1) * 4096 + (size_t)t * 8;
            short* lp = &lds[cur ^ 1][t * 8];
            gload_lds16(csh + gb, lp);           gload_lds16(csh + gb + 2048, lp + 2048);
            gload_lds16(csl + gb, lp + 4096);    gload_lds16(csl + gb + 2048, lp + 6144);
            gload_lds16(cdh + gb, lp + 8192);    gload_lds16(cdh + gb + 2048, lp + 10240);
            gload_lds16(cdl + gb, lp + 12288);   gload_lds16(cdl + gb + 2048, lp + 14336);
            #pragma unroll
            for (int rt = 0; rt < 4; ++rt) {
                un[rt][0] = *(const u16x8*)(cp[rt] + (cc + 1) * 64);
                un[rt][1] = *(const u16x8*)(cp[rt] + (cc + 1) * 64 + 32);
            }
        }
        const short* bufp = &lds[cur][0];
        #pragma unroll
        for (int st = 0; st < 2; ++st) {
            s16x8 As[4], Aa[4];
            #pragma unroll
            for (int rt = 0; rt < 4; ++rt) {
                #pragma unroll
                for (int i = 0; i < 8; ++i) {
                    unsigned int tb = ((unsigned int)uc[rt][st][i] >> sh_) & 3u;
                    unsigned short m = (tb & 1u) ? (unsigned short)0x3F80 : (unsigned short)0;
                    As[rt][i] = (short)m;
                    Aa[rt][i] = (short)(m | ((tb & 2u) << 14));
                }
            }
            #pragma unroll
            for (int n = 0; n < 4; ++n) {
                int off = ((st * 4 + lg) * 64 + n * 16 + lr) * 8;
                s16x8 Bs0 = *(const s16x8*)(bufp + off);
                s16x8 Bs1 = *(const s16x8*)(bufp + 4096 + off);
                s16x8 Bd0 = *(const s16x8*)(bufp + 8192 + off);
                s16x8 Bd1 = *(const s16x8*)(bufp + 12288 + off);
                #pragma unroll
                for (int rt = 0; rt < 4; ++rt) {
                    acc[rt][n] = __builtin_amdgcn_mfma_f32_16x16x32_bf16(As[rt], Bs0, acc[rt][n], 0, 0, 0);
                    acc[rt][n] = __builtin_amdgcn_mfma_f32_16x16x32_bf16(As[rt], Bs1, acc[rt][n], 0, 0, 0);
                    acc[rt][n] = __builtin_amdgcn_mfma_f32_16x16x32_bf16(Aa[rt], Bd0, acc[rt][n], 0, 0, 0);
                    acc[rt][n] = __builtin_amdgcn_mfma_f32_16x16x32_bf16(Aa[rt], Bd1, acc[rt][n], 0, 0, 0);
                }
            }
        }
        if (cc < 7) {
            #pragma unroll
            for (int rt = 0; rt < 4; ++rt) { uc[rt][0] = un[rt][0]; uc[rt][1] = un[rt][1]; }
        }
        __syncthreads();
        cur ^= 1;
    }
    float* dst = npart + (((size_t)q * NBATCH + b) * NV + v0) * DD;
    #pragma unroll
    for (int rt = 0; rt < 4; ++rt)
        #pragma unroll
        for (int n = 0; n < 4; ++n)
            #pragma unroll
            for (int r = 0; r < 4; ++r)
                dst[(size_t)(rt * 16 + lg * 4 + r) * DD + n * 16 + lr] = acc[rt][n][r];
}

// ---------------------------------------------------------------------------
// K4: v_emb=relu(sum_q npart+vb); av=tanh([g|v_emb]@Wg^T+bg); GRU -> out (f32)
// grid 256 x 512, 4 row-iterations per block (weights staged once).
// ---------------------------------------------------------------------------
__global__ __launch_bounds__(512) void k_gru(
    const float* __restrict__ npart, const float* __restrict__ vars,
    const float* __restrict__ gv, const float* __restrict__ vb,
    const float* __restrict__ Wg, const float* __restrict__ bg,
    const float* __restrict__ Wz, const float* __restrict__ Uz, const float* __restrict__ bz,
    const float* __restrict__ Wr, const float* __restrict__ Ur, const float* __restrict__ brr,
    const float* __restrict__ Wh, const float* __restrict__ Uh, const float* __restrict__ bh,
    float* __restrict__ out)
{
    __shared__ float sWg[72][65];
    __shared__ float sWz[64][65], sUz[64][65];
    __shared__ float sWr[64][65], sUr[64][65];
    __shared__ float sWh[64][65], sUh[64][65];
    __shared__ float scat[8][72];
    __shared__ float sprev[8][64];
    __shared__ float sav[8][64];
    __shared__ float srp[8][64];
    int t = threadIdx.x;
    for (int i = t * 4; i < 4608; i += 2048) {
        fx4 g4 = *(const fx4*)(Wg + i);
        int dout = i / 72, j = i - dout * 72;
        #pragma unroll
        for (int jj = 0; jj < 4; ++jj) sWg[j + jj][dout] = g4[jj];
    }
    for (int i = t * 4; i < 4096; i += 2048) {
        int dout = i >> 6, k = i & 63;
        fx4 a;
        a = *(const fx4*)(Wz + i);
        #pragma unroll
        for (int jj = 0; jj < 4; ++jj) sWz[k + jj][dout] = a[jj];
        a = *(const fx4*)(Uz + i);
        #pragma unroll
        for (int jj = 0; jj < 4; ++jj) sUz[k + jj][dout] = a[jj];
        a = *(const fx4*)(Wr + i);
        #pragma unroll
        for (int jj = 0; jj < 4; ++jj) sWr[k + jj][dout] = a[jj];
        a = *(const fx4*)(Ur + i);
        #pragma unroll
        for (int jj = 0; jj < 4; ++jj) sUr[k + jj][dout] = a[jj];
        a = *(const fx4*)(Wh + i);
        #pragma unroll
        for (int jj = 0; jj < 4; ++jj) sWh[k + jj][dout] = a[jj];
        a = *(const fx4*)(Uh + i);
        #pragma unroll
        for (int jj = 0; jj < 4; ++jj) sUh[k + jj][dout] = a[jj];
    }
    int rr = t >> 6, dout = t & 63;
    const size_t qs = (size_t)NBATCH * NV * DD;
    #pragma unroll 1
    for (int it = 0; it < 4; ++it) {
        size_t row = (size_t)blockIdx.x * 32 + it * 8 + rr;
        float prev = vars[row * 64 + dout];
        float ve = vb[dout];
        #pragma unroll
        for (int s = 0; s < 16; ++s) ve += npart[(size_t)s * qs + row * 64 + dout];
        ve = fmaxf(ve, 0.f);
        scat[rr][8 + dout] = ve;
        if (dout < 8) scat[rr][dout] = gv[row * 8 + dout];
        sprev[rr][dout] = prev;
        __syncthreads();
        float a = bg[dout];
        for (int j = 0; j < 72; ++j) a += scat[rr][j] * sWg[j][dout];
        float av = 1.f - 2.f / (__expf(2.f * a) + 1.f);
        sav[rr][dout] = av;
        __syncthreads();
        float zi = bz[dout], ri = brr[dout], hwa = 0.f;
        for (int k = 0; k < 64; ++k) {
            float ak = sav[rr][k], pk = sprev[rr][k];
            zi += ak * sWz[k][dout] + pk * sUz[k][dout];
            ri += ak * sWr[k][dout] + pk * sUr[k][dout];
            hwa += ak * sWh[k][dout];
        }
        float z = 1.f / (1.f + __expf(-zi));
        float rgate = 1.f / (1.f + __expf(-ri));
        srp[rr][dout] = rgate * prev;
        __syncthreads();
        float hin = bh[dout] + hwa;
        for (int k = 0; k < 64; ++k) hin += srp[rr][k] * sUh[k][dout];
        float ht = 1.f - 2.f / (__expf(2.f * hin) + 1.f);
        out[row * 64 + dout] = (1.f - z) * prev + z * ht;
        __syncthreads();
    }
}

// ---------------------------------------------------------------------------
extern "C" void kernel_launch(void* const* d_in, const int* in_sizes, int n_in,
                              void* d_out, int out_size, void* d_ws, size_t ws_size,
                              hipStream_t stream) {
    (void)in_sizes; (void)n_in; (void)out_size; (void)ws_size;
    const float* vars = (const float*)d_in[0];
    const float* gv   = (const float*)d_in[1];
    const float* cmat = (const float*)d_in[2];
    const float* cblk = (const float*)d_in[4];
    const float* vblk = (const float*)d_in[5];
    const float* vb   = (const float*)d_in[6];
    const float* cb   = (const float*)d_in[7];
    const float* Wg   = (const float*)d_in[8];
    const float* bg   = (const float*)d_in[9];
    const float* Wz   = (const float*)d_in[10];
    const float* Uz   = (const float*)d_in[11];
    const float* bz   = (const float*)d_in[12];
    const float* Wr   = (const float*)d_in[13];
    const float* Ur   = (const float*)d_in[14];
    const float* br_  = (const float*)d_in[15];
    const float* Wh   = (const float*)d_in[16];
    const float* Uh   = (const float*)d_in[17];
    const float* bh   = (const float*)d_in[18];
    float* out = (float*)d_out;

    char* w = (char*)d_ws;
    const size_t MB = 1024 * 1024;
    char* qsh = w + 0 * MB;
    char* qsl = w + 1 * MB;          // each 512 KB used
    char* qdh = w + 2 * MB;
    char* qdl = w + 3 * MB;
    unsigned short* csh = (unsigned short*)(w + 4 * MB);
    unsigned short* csl = (unsigned short*)(w + 8 * MB);
    unsigned short* cdh = (unsigned short*)(w + 12 * MB);
    unsigned short* cdl = (unsigned short*)(w + 16 * MB);
    float* cfull         = (float*)(w + 20 * MB);           // 8 MB [B][NC][DD]
    float* npart         = (float*)(w + 28 * MB);           // 32 MB [16][B][NV][DD]
    unsigned short* comp = (unsigned short*)(w + 60 * MB);  // 16 MB [B][256][NC]

    k_prep_pv<<<256, 256, 0, stream>>>(vars, cblk, qsh, qsl, qdh, qdl);
    k_phaseA<<<256, 512, 0, stream>>>(cmat, qsh, qsl, qdh, qdl, cb, cfull, comp);
    k_projC<<<1024, 256, 0, stream>>>(cfull, vblk, csh, csl, cdh, cdl);
    k_phaseB<<<512, 256, 0, stream>>>(comp, csh, csl, cdh, cdl, npart);
    k_gru<<<256, 512, 0, stream>>>(npart, vars, gv, vb, Wg, bg,
                                   Wz, Uz, bz, Wr, Ur, br_, Wh, Uh, bh, out);
}